// Round 13
// baseline (233.278 us; speedup 1.0000x reference)
//
#include <hip/hip_runtime.h>

// MultiHeadSelfAttention  B=2 S=2048 D=1024 H=16 d=64, fp32 in/out.
// R12: R11 attn + double-buffered K/V staging, ONE barrier per iter.
//   R8 vs R11 showed attn is latency-bound on the per-iter chain (barrier ->
//   vmcnt drain -> ds_read -> MFMA -> exp), not LDS-pipe-bound. 2-stage
//   pipeline: preload tile0; each iter: barrier (drains loads issued a full
//   compute-phase ago = cheap) -> issue tile kt+1 into other buffer ->
//   compute tile kt. Load latency now overlaps compute.
// GEMMs/prep/swizzle unchanged from R8/R11.
// ws: Ksw 8M @0 | val_h 8M @8M | wq_t 6M @16M | wo_t 2M @22M | qkv 24M @24M
//     | x_h 8M @48M (dead after GEMM1, overwritten by Vsw)

#define D_MODEL 1024
#define NHEAD   16
#define HDIM    64
#define SEQ     2048
#define BATCH   2
#define NTOK    (BATCH * SEQ)

typedef float    f32x4 __attribute__((ext_vector_type(4)));
typedef _Float16 f16x8 __attribute__((ext_vector_type(8)));
typedef _Float16 f16x4 __attribute__((ext_vector_type(4)));

#define GLOBAL_LOAD_LDS16(gptr, lptr)                                            \
    __builtin_amdgcn_global_load_lds(                                            \
        (const __attribute__((address_space(1))) unsigned int*)(gptr),           \
        (__attribute__((address_space(3))) unsigned int*)(lptr), 16, 0, 0)

// ---------------- prep: x->fp16, W_qkv^T, W_out^T (one launch) ----------------
__global__ __launch_bounds__(256) void prep_kernel(
    const float* __restrict__ x, _Float16* __restrict__ xh,
    const float* __restrict__ Wqkv, _Float16* __restrict__ wq_t,
    const float* __restrict__ Wout, _Float16* __restrict__ wo_t)
{
    const int bx = blockIdx.x;
    const int tid = threadIdx.x;
    if (bx < 4096) {
        const int i = (bx * 256 + tid) * 4;
        const float4 v = *(const float4*)&x[i];
        f16x4 hh;
        hh[0] = (_Float16)v.x; hh[1] = (_Float16)v.y;
        hh[2] = (_Float16)v.z; hh[3] = (_Float16)v.w;
        *(f16x4*)&xh[i] = hh;
        return;
    }
    __shared__ float ts[64][65];
    const float* W; _Float16* Wt; int N, n0, k0;
    if (bx < 4096 + 768) {
        const int local = bx - 4096;
        W = Wqkv; Wt = wq_t; N = 3072;
        n0 = (local % 48) * 64; k0 = (local / 48) * 64;
    } else {
        const int local = bx - 4864;
        W = Wout; Wt = wo_t; N = 1024;
        n0 = (local % 16) * 64; k0 = (local / 16) * 64;
    }
    {
        const int r = tid >> 2, c = (tid & 3) << 4;
        const float* src = W + (size_t)(k0 + r) * N + n0 + c;
        #pragma unroll
        for (int u = 0; u < 4; ++u)
            *(float4*)&ts[r][c + u * 4] = *(const float4*)&src[u * 4];
    }
    __syncthreads();
    {
        const int n = tid >> 2, kg = (tid & 3) << 4;
        f16x8 v0, v1;
        #pragma unroll
        for (int j = 0; j < 8; ++j) {
            v0[j] = (_Float16)ts[kg + j][n];
            v1[j] = (_Float16)ts[kg + 8 + j][n];
        }
        _Float16* dst = Wt + (size_t)(n0 + n) * D_MODEL + k0 + kg;
        *(f16x8*)&dst[0] = v0;
        *(f16x8*)&dst[8] = v1;
    }
}

// ---------------- GEMM1: 128x128 tile, BK=32, 512 threads (8 waves of 32x64) ----------------
__global__ __launch_bounds__(512) void gemm_qkv_kernel(
    const _Float16* __restrict__ A, const _Float16* __restrict__ Bt,
    const float* __restrict__ bias, _Float16* __restrict__ Cout,
    int M, int N, int K)
{
    __shared__ _Float16 lds[2][4096];
    const int tid = threadIdx.x;
    const int wave = tid >> 6, lane = tid & 63;
    const int quad = lane >> 4, l16 = lane & 15;
    const int m0 = blockIdx.y * 128, n0 = blockIdx.x * 128;
    const int wr = wave >> 1, wc = wave & 1;

    f32x4 acc[2][4] = {};

    const bool isA = wave < 4;
    const _Float16* gsrc = isA ? (A + (size_t)m0 * K) : (Bt + (size_t)n0 * K);
    _Float16* ldst = isA ? &lds[0][0] : &lds[1][0];
    const int sbase = (wave & 3) * 2;

    for (int k0 = 0; k0 < K; k0 += 32) {
        __syncthreads();
        #pragma unroll
        for (int j = 0; j < 2; ++j) {
            const int seg = sbase + j;
            const int chunk = seg >> 1;
            const int row = ((seg & 1) << 6) | lane;
            GLOBAL_LOAD_LDS16(gsrc + (size_t)row * K + k0 + chunk * 8, ldst + seg * 512);
        }
        __syncthreads();

        f16x8 a[2], b[4];
        #pragma unroll
        for (int mt = 0; mt < 2; ++mt)
            a[mt] = *(const f16x8*)&lds[0][quad * 1024 + (wr * 32 + mt * 16 + l16) * 8];
        #pragma unroll
        for (int nt = 0; nt < 4; ++nt)
            b[nt] = *(const f16x8*)&lds[1][quad * 1024 + (wc * 64 + nt * 16 + l16) * 8];
        #pragma unroll
        for (int mt = 0; mt < 2; ++mt)
            #pragma unroll
            for (int nt = 0; nt < 4; ++nt)
                acc[mt][nt] = __builtin_amdgcn_mfma_f32_16x16x32_f16(a[mt], b[nt], acc[mt][nt], 0, 0, 0);
    }

    #pragma unroll
    for (int nt = 0; nt < 4; ++nt) {
        const int col = n0 + wc * 64 + nt * 16 + l16;
        const float bv = bias[col];
        #pragma unroll
        for (int mt = 0; mt < 2; ++mt) {
            #pragma unroll
            for (int r = 0; r < 4; ++r) {
                const int row = m0 + wr * 32 + mt * 16 + quad * 4 + r;
                Cout[(size_t)row * N + col] = (_Float16)(acc[mt][nt][r] + bv);
            }
        }
    }
}

// ---------------- GEMM2: 128x64 tile, BK=32, 512 threads (8 waves of 32x32), fp32 out ----------------
__global__ __launch_bounds__(512) void gemm_out_kernel(
    const _Float16* __restrict__ A, const _Float16* __restrict__ Bt,
    const float* __restrict__ bias, float* __restrict__ Cout)
{
    const int K = D_MODEL, N = D_MODEL;
    __shared__ _Float16 ldsA[4096];
    __shared__ _Float16 ldsB[2048];
    const int tid = threadIdx.x;
    const int wave = tid >> 6, lane = tid & 63;
    const int quad = lane >> 4, l16 = lane & 15;
    const int m0 = blockIdx.y * 128, n0 = blockIdx.x * 64;
    const int wr = wave >> 1, wc = wave & 1;

    f32x4 acc[2][2] = {};

    for (int k0 = 0; k0 < K; k0 += 32) {
        __syncthreads();
        if (wave < 4) {
            #pragma unroll
            for (int j = 0; j < 2; ++j) {
                const int seg = wave * 2 + j;
                const int chunk = seg >> 1;
                const int row = ((seg & 1) << 6) | lane;
                GLOBAL_LOAD_LDS16(A + (size_t)(m0 + row) * K + k0 + chunk * 8, ldsA + seg * 512);
            }
        } else {
            const int seg = wave - 4;
            GLOBAL_LOAD_LDS16(Bt + (size_t)(n0 + lane) * K + k0 + seg * 8, ldsB + seg * 512);
        }
        __syncthreads();

        f16x8 a[2], b[2];
        #pragma unroll
        for (int mt = 0; mt < 2; ++mt)
            a[mt] = *(const f16x8*)&ldsA[quad * 1024 + (wr * 32 + mt * 16 + l16) * 8];
        #pragma unroll
        for (int nt = 0; nt < 2; ++nt)
            b[nt] = *(const f16x8*)&ldsB[quad * 512 + (wc * 32 + nt * 16 + l16) * 8];
        #pragma unroll
        for (int mt = 0; mt < 2; ++mt)
            #pragma unroll
            for (int nt = 0; nt < 2; ++nt)
                acc[mt][nt] = __builtin_amdgcn_mfma_f32_16x16x32_f16(a[mt], b[nt], acc[mt][nt], 0, 0, 0);
    }

    #pragma unroll
    for (int nt = 0; nt < 2; ++nt) {
        const int col = n0 + wc * 32 + nt * 16 + l16;
        const float bv = bias[col];
        #pragma unroll
        for (int mt = 0; mt < 2; ++mt) {
            #pragma unroll
            for (int r = 0; r < 4; ++r) {
                const int row = m0 + wr * 32 + mt * 16 + quad * 4 + r;
                Cout[(size_t)row * N + col] = acc[mt][nt][r] + bv;
            }
        }
    }
}

// ---------------- K,V slices of qkv -> swizzled MFMA-ready layouts ----------------
__global__ __launch_bounds__(256) void swizzle_kv_kernel(
    const _Float16* __restrict__ qkv,
    _Float16* __restrict__ Ksw, _Float16* __restrict__ Vsw)
{
    __shared__ _Float16 ts[64][72];
    const int tid = threadIdx.x;
    const int s0 = blockIdx.x * 64, h = blockIdx.y, b = blockIdx.z;
    const size_t hsz = (size_t)8 * SEQ * 8;
    _Float16* kh = Ksw + (size_t)(b * NHEAD + h) * hsz;
    _Float16* vh = Vsw + (size_t)(b * NHEAD + h) * hsz;

    {
        const int s = s0 + (tid >> 2);
        const int dg = (tid & 3) << 4;
        const _Float16* src = qkv + (size_t)(b * SEQ + s) * (3 * D_MODEL) + h * (3 * HDIM) + HDIM + dg;
        const f16x8 v0 = *(const f16x8*)&src[0];
        const f16x8 v1 = *(const f16x8*)&src[8];
        const int c0 = dg >> 3;
        *(f16x8*)&kh[((size_t)c0 * SEQ + s) * 8]       = v0;
        *(f16x8*)&kh[((size_t)(c0 + 1) * SEQ + s) * 8] = v1;
    }
    {
        const int s = tid >> 2, dg = (tid & 3) << 4;
        const _Float16* src = qkv + (size_t)(b * SEQ + s0 + s) * (3 * D_MODEL) + h * (3 * HDIM) + 2 * HDIM + dg;
        *(f16x8*)&ts[s][dg]     = *(const f16x8*)&src[0];
        *(f16x8*)&ts[s][dg + 8] = *(const f16x8*)&src[8];
    }
    __syncthreads();
    {
        const int d = tid >> 2, sg = (tid & 3) << 4;
        f16x8 v0, v1;
        #pragma unroll
        for (int j = 0; j < 8; ++j) { v0[j] = ts[sg + j][d]; v1[j] = ts[sg + 8 + j][d]; }
        const int cs0 = (s0 + sg) >> 3;
        *(f16x8*)&vh[((size_t)cs0 * HDIM + d) * 8]       = v0;
        *(f16x8*)&vh[((size_t)(cs0 + 1) * HDIM + d) * 8] = v1;
    }
}

// ---------------- attn v5: R11 + double-buffered staging, 1 barrier/iter ----------------
// Kst[2]/Vst[2]: 8KB each buffer pair; Ps 4 waves x [q 32][key 64 pad 72] 18KB; total 50KB.
// Wave w owns q rows q0+w*32..+31 (2 m-tiles). All MFMA K=32.
// Pipeline: preload buf0; iter kt: barrier -> issue kt+1 into buf[p^1] -> compute buf[p].
__global__ __launch_bounds__(256) void attn_mfma_kernel(
    const _Float16* __restrict__ qkv,
    const _Float16* __restrict__ Ksw, const _Float16* __restrict__ Vsw,
    _Float16* __restrict__ val)
{
    __shared__ _Float16 Kst[2][4096];          // [buf][c 8][key 64][8]
    __shared__ _Float16 Vst[2][4096];          // [buf][cs 8][d 64][8]
    __shared__ _Float16 Ps[4 * 32 * 72];       // 18KB

    const int tid = threadIdx.x;
    const int wave = tid >> 6, lane = tid & 63;
    const int quad = lane >> 4, l16 = lane & 15;
    const int qt = blockIdx.x, h = blockIdx.y, b = blockIdx.z;
    const int q0 = qt * 128;

    const size_t hsz = (size_t)8 * SEQ * 8;
    const _Float16* kh = Ksw + (size_t)(b * NHEAD + h) * hsz;
    const _Float16* vh = Vsw + (size_t)(b * NHEAD + h) * hsz;

    // Q B-fragments for this wave's 32 q rows, scaled log2(e)/8
    f16x8 qf[2][2];
    #pragma unroll
    for (int qt2 = 0; qt2 < 2; ++qt2) {
        const int row = q0 + wave * 32 + qt2 * 16 + l16;
        const _Float16* src = qkv + (size_t)(b * SEQ + row) * (3 * D_MODEL) + h * (3 * HDIM) + quad * 8;
        const f16x8 t0 = *(const f16x8*)(src);
        const f16x8 t1 = *(const f16x8*)(src + 32);
        #pragma unroll
        for (int j = 0; j < 8; ++j) {
            qf[qt2][0][j] = (_Float16)((float)t0[j] * 0.1803368802f);
            qf[qt2][1][j] = (_Float16)((float)t1[j] * 0.1803368802f);
        }
    }

    f32x4 acc[2][4] = {};     // O: [qt2][nt]
    float rs[2] = {};         // l partial for q = qt2*16 + l16

    _Float16* psw = Ps + wave * (32 * 72);
    const int c = wave * 2;   // this wave's two chunk indices c, c+1

    // preload tile 0 into buffer 0
    #pragma unroll
    for (int jj = 0; jj < 2; ++jj) {
        GLOBAL_LOAD_LDS16(kh + ((size_t)(c + jj) * SEQ + lane) * 8, &Kst[0][((c + jj) * 64 + lane) * 8]);
        GLOBAL_LOAD_LDS16(vh + ((size_t)(c + jj) * HDIM + lane) * 8, &Vst[0][((c + jj) * 64 + lane) * 8]);
    }

    for (int kt = 0; kt < SEQ / 64; ++kt) {
        const int p = kt & 1;
        __syncthreads();   // drains vmcnt: buf[p] loads (issued a full compute-phase ago) done;
                           // all waves finished reading buf[p^1] in iter kt-1.
        if (kt + 1 < SEQ / 64) {
            #pragma unroll
            for (int jj = 0; jj < 2; ++jj) {
                GLOBAL_LOAD_LDS16(kh + ((size_t)(c + jj) * SEQ + (kt + 1) * 64 + lane) * 8,
                                  &Kst[p ^ 1][((c + jj) * 64 + lane) * 8]);
                GLOBAL_LOAD_LDS16(vh + ((size_t)((kt + 1) * 8 + c + jj) * HDIM + lane) * 8,
                                  &Vst[p ^ 1][((c + jj) * 64 + lane) * 8]);
            }
        }

        // S^T = K Q^T : mt = key tile, kA reused across the 2 q-tiles
        #pragma unroll
        for (int mt = 0; mt < 4; ++mt) {
            const f16x8 kA0 = *(const f16x8*)&Kst[p][(quad * 64 + mt * 16 + l16) * 8];
            const f16x8 kA1 = *(const f16x8*)&Kst[p][((4 + quad) * 64 + mt * 16 + l16) * 8];
            #pragma unroll
            for (int qt2 = 0; qt2 < 2; ++qt2) {
                f32x4 s = {};
                s = __builtin_amdgcn_mfma_f32_16x16x32_f16(kA0, qf[qt2][0], s, 0, 0, 0);
                s = __builtin_amdgcn_mfma_f32_16x16x32_f16(kA1, qf[qt2][1], s, 0, 0, 0);
                const float p0 = __builtin_amdgcn_exp2f(s[0]);
                const float p1 = __builtin_amdgcn_exp2f(s[1]);
                const float p2 = __builtin_amdgcn_exp2f(s[2]);
                const float p3 = __builtin_amdgcn_exp2f(s[3]);
                rs[qt2] += (p0 + p1) + (p2 + p3);
                uint2 w;
                w.x = __builtin_bit_cast(unsigned, __builtin_amdgcn_cvt_pkrtz(p0, p1));
                w.y = __builtin_bit_cast(unsigned, __builtin_amdgcn_cvt_pkrtz(p2, p3));
                *(uint2*)&psw[(qt2 * 16 + l16) * 72 + mt * 16 + quad * 4] = w;
            }
        }
        // intra-wave RAW on psw: same-wave DS ordering via lgkmcnt, no barrier

        // O += P @ V : vf shared across the 2 q-tiles
        f16x8 pA[2][2];
        #pragma unroll
        for (int qt2 = 0; qt2 < 2; ++qt2) {
            pA[qt2][0] = *(const f16x8*)&psw[(qt2 * 16 + l16) * 72 + quad * 8];
            pA[qt2][1] = *(const f16x8*)&psw[(qt2 * 16 + l16) * 72 + 32 + quad * 8];
        }
        #pragma unroll
        for (int nt = 0; nt < 4; ++nt) {
            const f16x8 v0 = *(const f16x8*)&Vst[p][(quad * 64 + nt * 16 + l16) * 8];
            const f16x8 v1 = *(const f16x8*)&Vst[p][((4 + quad) * 64 + nt * 16 + l16) * 8];
            #pragma unroll
            for (int qt2 = 0; qt2 < 2; ++qt2) {
                acc[qt2][nt] = __builtin_amdgcn_mfma_f32_16x16x32_f16(pA[qt2][0], v0, acc[qt2][nt], 0, 0, 0);
                acc[qt2][nt] = __builtin_amdgcn_mfma_f32_16x16x32_f16(pA[qt2][1], v1, acc[qt2][nt], 0, 0, 0);
            }
        }
    }

    // l: reduce across quads (lanes l16+16k hold partials for q = qt2*16+l16)
    float invr[2][4];
    #pragma unroll
    for (int qt2 = 0; qt2 < 2; ++qt2) {
        rs[qt2] += __shfl_xor(rs[qt2], 16);
        rs[qt2] += __shfl_xor(rs[qt2], 32);
        const float inv = 1.f / rs[qt2];
        #pragma unroll
        for (int r = 0; r < 4; ++r)
            invr[qt2][r] = __shfl(inv, quad * 4 + r, 16);
    }

    #pragma unroll
    for (int qt2 = 0; qt2 < 2; ++qt2) {
        #pragma unroll
        for (int r = 0; r < 4; ++r) {
            const int row = b * SEQ + q0 + wave * 32 + qt2 * 16 + quad * 4 + r;
            #pragma unroll
            for (int nt = 0; nt < 4; ++nt) {
                const int col = h * HDIM + nt * 16 + l16;
                val[(size_t)row * D_MODEL + col] = (_Float16)(acc[qt2][nt][r] * invr[qt2][r]);
            }
        }
    }
}

extern "C" void kernel_launch(void* const* d_in, const int* in_sizes, int n_in,
                              void* d_out, int out_size, void* d_ws, size_t ws_size,
                              hipStream_t stream)
{
    const float* x     = (const float*)d_in[0];
    const float* W_qkv = (const float*)d_in[1];
    const float* b_qkv = (const float*)d_in[2];
    const float* W_out = (const float*)d_in[3];
    const float* b_out = (const float*)d_in[4];

    char* ws = (char*)d_ws;
    _Float16* Ksw   = (_Float16*)ws;                      // [32][8][2048][8]  8 MiB
    _Float16* val_h = (_Float16*)(ws + (8u << 20));       // [4096][1024]      8 MiB
    _Float16* wq_t  = (_Float16*)(ws + (16u << 20));      // [3072][1024]      6 MiB
    _Float16* wo_t  = (_Float16*)(ws + (22u << 20));      // [1024][1024]      2 MiB
    _Float16* qkv_h = (_Float16*)(ws + (24u << 20));      // [4096][3072]     24 MiB
    _Float16* x_h   = (_Float16*)(ws + (48u << 20));      // [4096][1024]      8 MiB
    _Float16* Vsw   = (_Float16*)(ws + (48u << 20));      // overwrites dead x_h

    prep_kernel<<<5120, 256, 0, stream>>>(x, x_h, W_qkv, wq_t, W_out, wo_t);
    gemm_qkv_kernel<<<dim3(3 * D_MODEL / 128, NTOK / 128), 512, 0, stream>>>(
        x_h, wq_t, b_qkv, qkv_h, NTOK, 3 * D_MODEL, D_MODEL);
    swizzle_kv_kernel<<<dim3(SEQ / 64, NHEAD, BATCH), 256, 0, stream>>>(qkv_h, Ksw, Vsw);
    attn_mfma_kernel<<<dim3(SEQ / 128, NHEAD, BATCH), 256, 0, stream>>>(qkv_h, Ksw, Vsw, val_h);
    gemm_out_kernel<<<dim3(D_MODEL / 64, NTOK / 128), 512, 0, stream>>>(
        val_h, wo_t, b_out, (float*)d_out);
}